// Round 2
// baseline (55.186 us; speedup 1.0000x reference)
//
#include <hip/hip_runtime.h>
#include <math.h>

// Problem constants (fixed by the reference)
#define H_VAL   7500.0f
#define EH_VAL  750.0f          // 0.1f * 7500.0f, fp32-exact
#define N_DIM   64
#define T_DIM   65536
#define BLOCKS_PER_N 32
#define THREADS 256
#define T_PER_BLOCK (T_DIM / BLOCKS_PER_N)   // 2048
#define ITERS (T_PER_BLOCK / THREADS)        // 8

__device__ __forceinline__ float dev_nan() { return __uint_as_float(0x7fc00000u); }
__device__ __forceinline__ bool is_nan(float x) { return x != x; }

// ws layout per (n,c): 8 floats at ws[n*32 + c*8]:
//   [0]=sum_all [1]=sum_o [2]=sum_u [3]=sum_e [4]=cnt_o [5]=cnt_u [6]=cnt_e [7]=pad
__global__ __launch_bounds__(THREADS, 8) void mae_stage1(
        const float* __restrict__ outp, const float* __restrict__ tgtp,
        float* __restrict__ ws) {
    const int n = blockIdx.x / BLOCKS_PER_N;
    const int slice = blockIdx.x % BLOCKS_PER_N;
    const int t0 = slice * T_PER_BLOCK;
    const float h = H_VAL;
    const float eh = EH_VAL;

    // 16 float accumulators per lane: v[c*4 + {0:all,1:o,2:u,3:e}]
    float v[16];
    #pragma unroll
    for (int i = 0; i < 16; ++i) v[i] = 0.0f;
    // wave-uniform integer counters (fed by ballot popcounts)
    int co[4] = {0, 0, 0, 0};
    int cu[4] = {0, 0, 0, 0};
    int ce[4] = {0, 0, 0, 0};

    const float4* o4 = reinterpret_cast<const float4*>(outp) + (size_t)n * T_DIM;
    const float4* t4 = reinterpret_cast<const float4*>(tgtp) + (size_t)n * T_DIM;

    #pragma unroll
    for (int it = 0; it < ITERS; ++it) {
        const int t = t0 + it * THREADS + (int)threadIdx.x;
        const float4 ov = o4[t];
        const float4 tv = t4[t];
        const float os[4] = {ov.x, ov.y, ov.z, ov.w};
        const float ts[4] = {tv.x, tv.y, tv.z, tv.w};
        #pragma unroll
        for (int c = 0; c < 4; ++c) {
            const float traw = ts[c];
            // over-bin: clamp condition AND tc==h coincide as (traw>=h)||(traw<0)
            const bool bo = (traw >= h) || (traw < 0.0f);
            const float tc = bo ? h : traw;
            const float d = fabsf(os[c] - tc);
            const bool bu = (traw == 0.0f);
            const bool be = (traw > 0.0f) && (traw < eh);

            v[c * 4 + 0] += d;                     // sum over ALL elements
            v[c * 4 + 1] += bo ? d : 0.0f;         // sum over-horizon
            v[c * 4 + 2] += bu ? d : 0.0f;         // sum target==0 (d=|o|)
            v[c * 4 + 3] += be ? d : 0.0f;         // sum early in-horizon

            co[c] += __popcll(__ballot(bo));       // wave-uniform SALU counts
            cu[c] += __popcll(__ballot(bu));
            ce[c] += __popcll(__ballot(be));
        }
    }

    // Split-butterfly reduce: 16 values across 64 lanes in 17 shuffles.
    // Rounds r=0..3 (dist 1,2,4,8): each lane keeps half its slots, adds
    // partner's matching half. Final slot owned by lane =
    //   bit-reversal of (lane & 15) over 4 bits.
    const int lane = threadIdx.x & 63;
    #pragma unroll
    for (int r = 0; r < 4; ++r) {
        const int dist = 1 << r;
        const bool hi = (lane >> r) & 1;
        const int cnt = 8 >> r;
        #pragma unroll
        for (int j = 0; j < cnt; ++j) {
            const float send = hi ? v[j] : v[j + cnt];
            const float recv = __shfl_xor(send, dist, 64);
            v[j] = (hi ? v[j + cnt] : v[j]) + recv;
        }
    }
    v[0] += __shfl_xor(v[0], 16, 64);
    v[0] += __shfl_xor(v[0], 32, 64);
    const int slot = ((lane & 1) << 3) | (((lane >> 1) & 1) << 2) |
                     (((lane >> 2) & 1) << 1) | ((lane >> 3) & 1);

    __shared__ float lsum[4][16];
    __shared__ int   lcnt[4][12];
    const int wave = threadIdx.x >> 6;
    if (lane < 16) lsum[wave][slot] = v[0];
    if (lane == 0) {
        #pragma unroll
        for (int c = 0; c < 4; ++c) {
            lcnt[wave][c * 3 + 0] = co[c];
            lcnt[wave][c * 3 + 1] = cu[c];
            lcnt[wave][c * 3 + 2] = ce[c];
        }
    }
    __syncthreads();
    if (threadIdx.x < 16) {
        const int i = threadIdx.x;
        const float s = lsum[0][i] + lsum[1][i] + lsum[2][i] + lsum[3][i];
        const int c = i >> 2, k = i & 3;
        atomicAdd(&ws[n * 32 + c * 8 + k], s);
    }
    if (threadIdx.x < 12) {
        const int i = threadIdx.x;
        const int s = lcnt[0][i] + lcnt[1][i] + lcnt[2][i] + lcnt[3][i];
        const int c = i / 3, k = i % 3;
        atomicAdd(&ws[n * 32 + c * 8 + 4 + k], (float)s);
    }
}

__global__ __launch_bounds__(256) void mae_stage2(
        const float* __restrict__ ws, float* __restrict__ outp) {
    const int i = threadIdx.x;            // 0..255 == (n,c) pair
    const int n = i >> 2, c = i & 3;
    const float* a = &ws[n * 32 + c * 8];

    const float sum_all = a[0], sum_o = a[1], sum_u = a[2], sum_e = a[3];
    const float cnt_o = a[4], cnt_u = a[5], cnt_e = a[6];
    const float cnt_in = (float)T_DIM - cnt_o - cnt_u;   // exact in fp32
    const float sum_in = sum_all - sum_o - sum_u;

    const float m_o  = (cnt_o  > 0.0f) ? sum_o  / cnt_o  : dev_nan();
    const float m_in = (cnt_in > 0.0f) ? sum_in / cnt_in : dev_nan();
    const float m_u  = (cnt_u  > 0.0f) ? sum_u  / cnt_u  : dev_nan();
    const float m_e  = (cnt_e  > 0.0f) ? sum_e  / cnt_e  : dev_nan();

    auto nm2 = [](float x, float y) {
        const bool vx = !is_nan(x), vy = !is_nan(y);
        const float s  = (vx ? x : 0.0f) + (vy ? y : 0.0f);
        const float cc = (vx ? 1.0f : 0.0f) + (vy ? 1.0f : 0.0f);
        return (cc > 0.0f) ? s / cc : dev_nan();
    };
    const float in_comb = nm2(m_u, m_in);
    const float w       = nm2(m_o, in_comb);

    float vals[4] = {w, in_comb, m_o, m_e};   // -> wMAE, inMAE, oMAE, eMAE
    float sums[4], cnts[4];
    #pragma unroll
    for (int j = 0; j < 4; ++j) {
        const bool valid = !is_nan(vals[j]);
        sums[j] = valid ? vals[j] : 0.0f;
        cnts[j] = valid ? 1.0f : 0.0f;
    }
    #pragma unroll
    for (int j = 0; j < 4; ++j) {
        #pragma unroll
        for (int off = 32; off > 0; off >>= 1) {
            sums[j] += __shfl_down(sums[j], off, 64);
            cnts[j] += __shfl_down(cnts[j], off, 64);
        }
    }
    __shared__ float ls[4][8];
    const int wave = threadIdx.x >> 6;
    const int lane = threadIdx.x & 63;
    if (lane == 0) {
        #pragma unroll
        for (int j = 0; j < 4; ++j) { ls[wave][j] = sums[j]; ls[wave][j + 4] = cnts[j]; }
    }
    __syncthreads();
    if (threadIdx.x == 0) {
        #pragma unroll
        for (int j = 0; j < 4; ++j) {
            const float s  = ls[0][j] + ls[1][j] + ls[2][j] + ls[3][j];
            const float cc = ls[0][j + 4] + ls[1][j + 4] + ls[2][j + 4] + ls[3][j + 4];
            outp[j] = (cc > 0.0f) ? s / cc : dev_nan();
        }
    }
}

extern "C" void kernel_launch(void* const* d_in, const int* in_sizes, int n_in,
                              void* d_out, int out_size, void* d_ws, size_t ws_size,
                              hipStream_t stream) {
    const float* out_rsd = (const float*)d_in[0];
    const float* tgt_rsd = (const float*)d_in[1];
    float* outv = (float*)d_out;
    float* ws = (float*)d_ws;

    // Zero the 8 KB accumulator workspace every call (harness does not re-poison).
    hipMemsetAsync(ws, 0, N_DIM * 32 * sizeof(float), stream);

    mae_stage1<<<N_DIM * BLOCKS_PER_N, THREADS, 0, stream>>>(out_rsd, tgt_rsd, ws);
    mae_stage2<<<1, 256, 0, stream>>>(ws, outv);
}